// Round 11
// baseline (843.291 us; speedup 1.0000x reference)
//
#include <hip/hip_runtime.h>
#include <hip/hip_bf16.h>
#include <math.h>

// Problem constants
#define BATCH 32
#define IN_LEN 28
#define NN 2048
#define E 256
#define H 512
#define N_LAYERS 3
#define OUT_LEN 28
#define M_ROWS (BATCH * NN)   // 65536

typedef unsigned short u16;
typedef unsigned int   u32;
typedef __attribute__((ext_vector_type(8))) short short8;   // 8 f16 (4 VGPRs)
typedef __attribute__((ext_vector_type(4))) float f32x4;    // MFMA accumulator

// ---- fp16 split helpers (RNE casts) ----------------------------------------
__device__ __forceinline__ u16 f2h(float x) {
    union { _Float16 h; u16 u; } v; v.h = (_Float16)x; return v.u;
}
__device__ __forceinline__ float h2f(u16 u) {
    union { _Float16 h; u16 u; } v; v.u = u; return (float)v.h;
}

// async global -> LDS, 16 B per lane. LDS dest = wave-uniform base + lane*16.
__device__ __forceinline__ void gload_lds16(const void* g, void* l) {
    __builtin_amdgcn_global_load_lds(
        (const __attribute__((address_space(1))) void*)g,
        (__attribute__((address_space(3))) void*)l, 16, 0, 0);
}

// ---------------------------------------------------------------------------
// Split BOTH weight tensors into fp16 hi/lo (one launch).
// ---------------------------------------------------------------------------
__global__ __launch_bounds__(256)
void k_split2(const float* __restrict__ w1, const float* __restrict__ w2,
              u16* __restrict__ hi, u16* __restrict__ lo, int nW)
{
    int i = blockIdx.x * 256 + threadIdx.x;
    float v = (i < nW) ? w1[i] : w2[i - nW];
    u16 h = f2h(v);
    hi[i] = h;
    lo[i] = f2h(v - h2f(h));
}

// ---------------------------------------------------------------------------
// Kernel 1: ts = flat @ W_ts^T + b_ts ; h = concat([ts, node_emb]) -> split
// Vectorized: each thread owns a COLUMN PAIR and writes u32 (2 x fp16).
// Waves 0-1 (tid<128): ts col pair (2c, 2c+1). Waves 2-3: emb col pair.
// ---------------------------------------------------------------------------
__global__ __launch_bounds__(256)
void k_ts(const float* __restrict__ x_node, const float* __restrict__ node_emb,
          const float* __restrict__ W_ts, const float* __restrict__ b_ts,
          u16* __restrict__ hhi, u16* __restrict__ hlo)
{
    __shared__ float xs[IN_LEN][64];
    const int tid = threadIdx.x;
    const int b   = blockIdx.y;
    const int n0  = blockIdx.x * 64;
    const int c   = tid & 127;        // col pair index
    const int sec = tid >> 7;         // 0: ts, 1: emb (wave-uniform)

    for (int idx = tid; idx < IN_LEN * 64; idx += 256) {
        int l = idx >> 6, i = idx & 63;
        xs[l][i] = x_node[((size_t)b * IN_LEN + l) * NN + n0 + i];
    }

    float w0[IN_LEN], w1[IN_LEN];
    float bias0 = 0.f, bias1 = 0.f;
    if (sec == 0) {
        #pragma unroll
        for (int j = 0; j < IN_LEN; j++) {
            w0[j] = W_ts[(2 * c) * IN_LEN + j];
            w1[j] = W_ts[(2 * c + 1) * IN_LEN + j];
        }
        bias0 = b_ts[2 * c];
        bias1 = b_ts[2 * c + 1];
    }
    __syncthreads();

    for (int i = 0; i < 64; i++) {
        size_t row = (size_t)b * NN + n0 + i;
        u32* oh = (u32*)(hhi + row * H);
        u32* ol = (u32*)(hlo + row * H);
        float v0, v1;
        int oc;
        if (sec == 0) {
            v0 = bias0; v1 = bias1;
            #pragma unroll
            for (int j = 0; j < IN_LEN; j++) {
                float x = xs[j][i];
                v0 += x * w0[j];
                v1 += x * w1[j];
            }
            oc = c;
        } else {
            const float2 ev = *(const float2*)&node_emb[(size_t)(n0 + i) * 256 + 2 * c];
            v0 = ev.x; v1 = ev.y;
            oc = 128 + c;
        }
        u16 h0 = f2h(v0), h1 = f2h(v1);
        oh[oc] = (u32)h0 | ((u32)h1 << 16);
        ol[oc] = (u32)f2h(v0 - h2f(h0)) | ((u32)f2h(v1 - h2f(h1)) << 16);
    }
}

// ---------------------------------------------------------------------------
// Kernel 2a: GEMM1  z = relu(h @ W1^T + b1), h split (3-term), z fp16 SINGLE.
// Tile 128x128, 4 waves, BK=32, all 4 tiles double-buffered (64 KB LDS),
// one barrier per K-step, XOR source swizzle, XCD-aware block decode.
// Epilogue: LDS-bounce then coalesced dwordx4 stores.
// ---------------------------------------------------------------------------
__global__ __launch_bounds__(256)
void k_gemm1(const u16* __restrict__ Ahi, const u16* __restrict__ Alo,
             const u16* __restrict__ Whi, const u16* __restrict__ Wlo,
             const float* __restrict__ bias, u16* __restrict__ Z)
{
    __shared__ __align__(16) u16 smem[32768];   // 64 KB

    const int tid = threadIdx.x;
    const int ln  = tid & 63;
    const int wv  = tid >> 6;

    const int id   = blockIdx.x;
    const int c    = (id >> 3) & 3;
    const int r    = (id & 7) | ((id >> 5) << 3);
    const int row0 = r * 128;
    const int col0 = c * 128;

    const int rbase = (wv & 1) * 64;
    const int cbase = (wv >> 1) * 64;

    const int lr = ln >> 2;
    const int lc = ln & 3;

    const u16* sgsrc; int sofs; int tb;
    if      (wv == 0) { sgsrc = Ahi; sofs = 0;     tb = row0; }
    else if (wv == 1) { sgsrc = Alo; sofs = 8192;  tb = row0; }
    else if (wv == 2) { sgsrc = Whi; sofs = 16384; tb = col0; }
    else              { sgsrc = Wlo; sofs = 24576; tb = col0; }

    auto stage = [&](int p, int kt) {
        u16* dstbuf = smem + sofs + p * 4096;
        #pragma unroll
        for (int i = 0; i < 8; i++) {
            int row = i * 16 + lr;
            int sc  = lc ^ ((row >> 1) & 3);
            gload_lds16(sgsrc + (size_t)(tb + row) * H + kt + sc * 8,
                        dstbuf + i * 512);
        }
    };

    f32x4 acc[4][4];
    #pragma unroll
    for (int m = 0; m < 4; m++)
        #pragma unroll
        for (int n = 0; n < 4; n++) acc[m][n] = (f32x4)(0.f);

    stage(0, 0);

    const int wl = ln & 15;

    for (int t = 0; t < 16; t++) {
        const int p = t & 1;
        __syncthreads();
        if (t + 1 < 16) stage(1 - p, (t + 1) * 32);

        const u16* bAh = smem + 0     + p * 4096;
        const u16* bAl = smem + 8192  + p * 4096;
        const u16* bWh = smem + 16384 + p * 4096;
        const u16* bWl = smem + 24576 + p * 4096;

        short8 ahi[4], alo[4], whi[4], wlo[4];
        #pragma unroll
        for (int m = 0; m < 4; m++) {
            int rr = rbase + m * 16 + wl;
            int cc = ((ln >> 4) ^ ((rr >> 1) & 3)) * 8;
            ahi[m] = *(const short8*)&bAh[rr * 32 + cc];
            alo[m] = *(const short8*)&bAl[rr * 32 + cc];
        }
        #pragma unroll
        for (int n = 0; n < 4; n++) {
            int wr = cbase + n * 16 + wl;
            int cc = ((ln >> 4) ^ ((wr >> 1) & 3)) * 8;
            whi[n] = *(const short8*)&bWh[wr * 32 + cc];
            wlo[n] = *(const short8*)&bWl[wr * 32 + cc];
        }
        #pragma unroll
        for (int m = 0; m < 4; m++)
            #pragma unroll
            for (int n = 0; n < 4; n++) {
                acc[m][n] = __builtin_amdgcn_mfma_f32_16x16x32_f16(ahi[m], whi[n], acc[m][n], 0, 0, 0);
                acc[m][n] = __builtin_amdgcn_mfma_f32_16x16x32_f16(ahi[m], wlo[n], acc[m][n], 0, 0, 0);
                acc[m][n] = __builtin_amdgcn_mfma_f32_16x16x32_f16(alo[m], whi[n], acc[m][n], 0, 0, 0);
            }
    }

    // ---- LDS-bounce epilogue ----
    __syncthreads();                         // staging LDS dead; reuse
    u16* zb = smem + wv * 4096;              // per-wave 64x64 u16 (8 KB)
    float bv[4];
    #pragma unroll
    for (int n = 0; n < 4; n++) bv[n] = bias[col0 + cbase + n * 16 + wl];
    #pragma unroll
    for (int m = 0; m < 4; m++)
        #pragma unroll
        for (int n = 0; n < 4; n++)
            #pragma unroll
            for (int rg = 0; rg < 4; rg++) {
                int row_l = m * 16 + (ln >> 4) * 4 + rg;
                zb[row_l * 64 + n * 16 + wl] =
                    f2h(fmaxf(acc[m][n][rg] + bv[n], 0.f));
            }
    const int cr = ln >> 3;          // 0..7
    const int cc = (ln & 7) * 8;     // u16 col
    #pragma unroll
    for (int p2 = 0; p2 < 8; p2++) {
        int row_l = cr + p2 * 8;
        uint4 v = *(const uint4*)&zb[row_l * 64 + cc];
        *(uint4*)&Z[(size_t)(row0 + rbase + row_l) * H + col0 + cbase + cc] = v;
    }
}

// ---------------------------------------------------------------------------
// Kernel 2b: GEMM2  h += z @ W2^T + b2, z fp16 single (2-term), out split.
// LDS K-loop = 48 KB. R8-style epilogue. HEAD=1: fused b/g head GEMV with
// per-row shfl reduce + one atomicAdd per row per wave.
// ---------------------------------------------------------------------------
template <int HEAD>
__global__ __launch_bounds__(256)
void k_gemm2(const u16* __restrict__ Z,
             const u16* __restrict__ Whi, const u16* __restrict__ Wlo,
             const float* __restrict__ bias,
             u16* HHi, u16* HLo,
             const float* __restrict__ Wb, const float* __restrict__ Wg,
             float* __restrict__ bSum, float* __restrict__ gSum)
{
    __shared__ __align__(16) u16 smem[24576];   // 48 KB

    const int tid = threadIdx.x;
    const int ln  = tid & 63;
    const int wv  = tid >> 6;

    const int id   = blockIdx.x;
    const int c    = (id >> 3) & 3;
    const int r    = (id & 7) | ((id >> 5) << 3);
    const int row0 = r * 128;
    const int col0 = c * 128;

    const int rbase = (wv & 1) * 64;
    const int cbase = (wv >> 1) * 64;

    const int lr = ln >> 2;
    const int lc = ln & 3;

    const u16* sgsrc; int sofs; int tb; int iofs; int niss;
    if      (wv == 0) { sgsrc = Z;   sofs = 0;     tb = row0;      iofs = 0;    niss = 4; }
    else if (wv == 3) { sgsrc = Z;   sofs = 0;     tb = row0 + 64; iofs = 2048; niss = 4; }
    else if (wv == 1) { sgsrc = Whi; sofs = 8192;  tb = col0;      iofs = 0;    niss = 8; }
    else              { sgsrc = Wlo; sofs = 16384; tb = col0;      iofs = 0;    niss = 8; }

    auto stage = [&](int p, int kt) {
        u16* dstbuf = smem + sofs + p * 4096 + iofs;
        #pragma unroll
        for (int i = 0; i < 8; i++) {
            if (i >= niss) break;
            int row = i * 16 + lr;
            int sc  = lc ^ ((row >> 1) & 3);
            gload_lds16(sgsrc + (size_t)(tb + row) * H + kt + sc * 8,
                        dstbuf + i * 512);
        }
    };

    f32x4 acc[4][4];
    #pragma unroll
    for (int m = 0; m < 4; m++)
        #pragma unroll
        for (int n = 0; n < 4; n++) acc[m][n] = (f32x4)(0.f);

    stage(0, 0);

    const int wl = ln & 15;

    for (int t = 0; t < 16; t++) {
        const int p = t & 1;
        __syncthreads();
        if (t + 1 < 16) stage(1 - p, (t + 1) * 32);

        const u16* bZ  = smem + 0     + p * 4096;
        const u16* bWh = smem + 8192  + p * 4096;
        const u16* bWl = smem + 16384 + p * 4096;

        short8 az[4], whi[4], wlo[4];
        #pragma unroll
        for (int m = 0; m < 4; m++) {
            int rr = rbase + m * 16 + wl;
            int cc = ((ln >> 4) ^ ((rr >> 1) & 3)) * 8;
            az[m] = *(const short8*)&bZ[rr * 32 + cc];
        }
        #pragma unroll
        for (int n = 0; n < 4; n++) {
            int wr = cbase + n * 16 + wl;
            int cc = ((ln >> 4) ^ ((wr >> 1) & 3)) * 8;
            whi[n] = *(const short8*)&bWh[wr * 32 + cc];
            wlo[n] = *(const short8*)&bWl[wr * 32 + cc];
        }
        #pragma unroll
        for (int m = 0; m < 4; m++)
            #pragma unroll
            for (int n = 0; n < 4; n++) {
                acc[m][n] = __builtin_amdgcn_mfma_f32_16x16x32_f16(az[m], whi[n], acc[m][n], 0, 0, 0);
                acc[m][n] = __builtin_amdgcn_mfma_f32_16x16x32_f16(az[m], wlo[n], acc[m][n], 0, 0, 0);
            }
    }

    // ---- LDS-bounce RMW epilogue ----
    __syncthreads();                              // staging LDS dead; reuse
    float* fb = (float*)smem + wv * 2048;         // per-wave 64x32 f32 (8 KB)

    const int cr  = ln >> 3;           // 0..7
    const int ccl = (ln & 7) * 4;      // u16 col within 32
    float pb[8], pg[8];
    if (HEAD) {
        #pragma unroll
        for (int p2 = 0; p2 < 8; p2++) { pb[p2] = 0.f; pg[p2] = 0.f; }
    }

    #pragma unroll
    for (int nh = 0; nh < 2; nh++) {
        #pragma unroll
        for (int m = 0; m < 4; m++)
            #pragma unroll
            for (int j = 0; j < 2; j++)
                #pragma unroll
                for (int rg = 0; rg < 4; rg++) {
                    int row_l = m * 16 + (ln >> 4) * 4 + rg;
                    fb[row_l * 32 + j * 16 + wl] = acc[m][nh * 2 + j][rg];
                }
        const int gc0 = col0 + cbase + nh * 32 + ccl;
        float4 bv = *(const float4*)&bias[gc0];
        float4 hb, hg;
        if (HEAD) {
            hb = *(const float4*)&Wb[gc0];
            hg = *(const float4*)&Wg[gc0];
        }
        #pragma unroll
        for (int p2 = 0; p2 < 8; p2++) {
            int row_l = cr + p2 * 8;
            size_t gidx = (size_t)(row0 + rbase + row_l) * H + gc0;
            uint2 uh = *(const uint2*)(HHi + gidx);
            uint2 ul = *(const uint2*)(HLo + gidx);
            float4 a = *(const float4*)&fb[row_l * 32 + ccl];
            float v0 = a.x + bv.x + h2f((u16)(uh.x & 0xFFFF)) + h2f((u16)(ul.x & 0xFFFF));
            float v1 = a.y + bv.y + h2f((u16)(uh.x >> 16))    + h2f((u16)(ul.x >> 16));
            float v2 = a.z + bv.z + h2f((u16)(uh.y & 0xFFFF)) + h2f((u16)(ul.y & 0xFFFF));
            float v3 = a.w + bv.w + h2f((u16)(uh.y >> 16))    + h2f((u16)(ul.y >> 16));
            if (HEAD) {
                pb[p2] += v0 * hb.x + v1 * hb.y + v2 * hb.z + v3 * hb.w;
                pg[p2] += v0 * hg.x + v1 * hg.y + v2 * hg.z + v3 * hg.w;
            }
            u16 h0 = f2h(v0), h1 = f2h(v1), h2 = f2h(v2), h3 = f2h(v3);
            uint2 oh, ol;
            oh.x = (u32)h0 | ((u32)h1 << 16);
            oh.y = (u32)h2 | ((u32)h3 << 16);
            ol.x = (u32)f2h(v0 - h2f(h0)) | ((u32)f2h(v1 - h2f(h1)) << 16);
            ol.y = (u32)f2h(v2 - h2f(h2)) | ((u32)f2h(v3 - h2f(h3)) << 16);
            *(uint2*)(HHi + gidx) = oh;
            *(uint2*)(HLo + gidx) = ol;
        }
    }

    if (HEAD) {
        #pragma unroll
        for (int p2 = 0; p2 < 8; p2++) {
            float sb = pb[p2], sg = pg[p2];
            #pragma unroll
            for (int off = 1; off < 8; off <<= 1) {
                sb += __shfl_xor(sb, off);
                sg += __shfl_xor(sg, off);
            }
            if ((ln & 7) == 0) {
                int grow = row0 + rbase + cr + p2 * 8;
                atomicAdd(&bSum[grow], sb);
                atomicAdd(&gSum[grow], sg);
            }
        }
    }
}

// ---------------------------------------------------------------------------
// Kernel 4: per-(b,n) SIR recurrence (applies head sigmoids itself).
// ---------------------------------------------------------------------------
__global__ __launch_bounds__(256)
void k_sir(const float* __restrict__ x_state,
           const float* __restrict__ bSum, const float* __restrict__ gSum,
           const float* __restrict__ bb, const float* __restrict__ bg,
           float* __restrict__ out)
{
    const int row = blockIdx.x * 256 + threadIdx.x;   // b*NN + n
    const int bb_ = row / NN;
    const int n   = row % NN;

    const float g = 1.f / (1.f + expf(-(gSum[row] + bg[0])));
    const float b = 1.f / (1.f + expf(-(bSum[row] + bb[0])));
    const float d = expf(-g);

    const float* xs = x_state + ((size_t)bb_ * IN_LEN) * (NN * 3) + (size_t)n * 3;

    float x1_prev = xs[1];
    float Ih_prev = x1_prev / g;
    float acc = 0.f;
    #pragma unroll 4
    for (int t = 1; t <= IN_LEN - 1; ++t) {
        float x1 = xs[(size_t)t * (NN * 3) + 1];
        float Ih = x1 / g;
        float Iin = fmaxf(Ih - Ih_prev + x1_prev, 0.f);
        acc = acc * d + Iin;
        Ih_prev = Ih;
        x1_prev = x1;
    }
    float ITm1 = acc * d;
    float Npop = xs[(size_t)(IN_LEN - 1) * (NN * 3) + 2];
    float RTm1 = Npop - xs[(size_t)(IN_LEN - 2) * (NN * 3) + 0];
    float STm1 = Npop - ITm1 - RTm1;
    float Iin0 = b * STm1 * ITm1 / Npop;
    float S = STm1 - Iin0;
    float I = d * (ITm1 + Iin0);

    float* op = out + ((size_t)bb_ * OUT_LEN) * NN + n;
    #pragma unroll 4
    for (int k = 0; k < OUT_LEN; k++) {
        float Iin = b * S * I / Npop;
        S = S - Iin;
        float Rin = g * I;
        I = d * (I + Iin);
        op[(size_t)k * NN] = Rin;
    }
}

// ---------------------------------------------------------------------------
extern "C" void kernel_launch(void* const* d_in, const int* in_sizes, int n_in,
                              void* d_out, int out_size, void* d_ws, size_t ws_size,
                              hipStream_t stream)
{
    const float* x_node   = (const float*)d_in[0];
    const float* x_state  = (const float*)d_in[1];
    const float* node_emb = (const float*)d_in[2];
    const float* W_ts     = (const float*)d_in[3];
    const float* b_ts     = (const float*)d_in[4];
    const float* enc_W1   = (const float*)d_in[5];
    const float* enc_b1   = (const float*)d_in[6];
    const float* enc_W2   = (const float*)d_in[7];
    const float* enc_b2   = (const float*)d_in[8];
    const float* Wb       = (const float*)d_in[9];
    const float* bb       = (const float*)d_in[10];
    const float* Wg       = (const float*)d_in[11];
    const float* bg       = (const float*)d_in[12];
    float* out = (float*)d_out;

    // Workspace: hhi 64M | hlo 64M | wHi 3M | wLo 3M | bSum | gSum | z (chunked)
    u16* hhi   = (u16*)d_ws;
    u16* hlo   = hhi + (size_t)M_ROWS * H;
    u16* wHi   = hlo + (size_t)M_ROWS * H;          // [6][512][512]
    u16* wLo   = wHi + (size_t)6 * H * H;
    float* bSum = (float*)(wLo + (size_t)6 * H * H);
    float* gSum = bSum + M_ROWS;
    u16* z     = (u16*)(gSum + M_ROWS);

    size_t used  = (size_t)((char*)z - (char*)d_ws);
    size_t avail = (ws_size > used) ? ws_size - used : 0;
    long long chunkLL = (long long)(avail / (H * sizeof(u16))) & ~1023LL;
    int chunk = (chunkLL > M_ROWS) ? M_ROWS : (int)chunkLL;
    if (chunk < 1024) chunk = 1024;
    // L3-locality: cap chunk so (h-chunk 2*rows*H*2B + z rows*H*2B + weights)
    // stays well inside the 256 MB Infinity Cache while a chunk runs all 3
    // layers. 32768 rows -> 64+32+12 = 108 MB working set.
    if (chunk > 32768) chunk = 32768;

    // zero the head accumulators (d_ws is re-poisoned before every call)
    hipMemsetAsync(bSum, 0, 2 * (size_t)M_ROWS * sizeof(float), stream);

    // weight conversion (redone every call)
    const int nW = N_LAYERS * H * H;   // 786432
    k_split2<<<2 * nW / 256, 256, 0, stream>>>(enc_W1, enc_W2, wHi, wLo, nW);

    // 1. build h (split)
    k_ts<<<dim3(NN / 64, BATCH), 256, 0, stream>>>(x_node, node_emb, W_ts, b_ts, hhi, hlo);

    // 2. encoder: row-chunks through ALL layers (rows independent end-to-end)
    //    so each chunk's h/z stay L3-resident across its 6 GEMM dispatches.
    for (int r = 0; r < M_ROWS; r += chunk) {
        int rows = (M_ROWS - r < chunk) ? (M_ROWS - r) : chunk;
        u16* hrhi = hhi + (size_t)r * H;
        u16* hrlo = hlo + (size_t)r * H;
        int nblk = (rows / 128) * 4;
        for (int l = 0; l < N_LAYERS; l++) {
            const u16* W1hi = wHi + (size_t)l * H * H;
            const u16* W1lo = wLo + (size_t)l * H * H;
            const u16* W2hi = wHi + (size_t)nW + (size_t)l * H * H;
            const u16* W2lo = wLo + (size_t)nW + (size_t)l * H * H;
            const float* b1 = enc_b1 + (size_t)l * H;
            const float* b2 = enc_b2 + (size_t)l * H;
            k_gemm1<<<nblk, 256, 0, stream>>>(hrhi, hrlo, W1hi, W1lo, b1, z);
            if (l < N_LAYERS - 1)
                k_gemm2<0><<<nblk, 256, 0, stream>>>(z, W2hi, W2lo, b2, hrhi, hrlo,
                                                     Wb, Wg, bSum + r, gSum + r);
            else
                k_gemm2<1><<<nblk, 256, 0, stream>>>(z, W2hi, W2lo, b2, hrhi, hrlo,
                                                     Wb, Wg, bSum + r, gSum + r);
        }
    }

    // 3. SIR recurrence + output (head sigmoid fused)
    k_sir<<<M_ROWS / 256, 256, 0, stream>>>(x_state, bSum, gSum, bb, bg, out);
}

// Round 12
// 785.048 us; speedup vs baseline: 1.0742x; 1.0742x over previous
//
#include <hip/hip_runtime.h>
#include <hip/hip_bf16.h>
#include <math.h>

// Problem constants
#define BATCH 32
#define IN_LEN 28
#define NN 2048
#define E 256
#define H 512
#define N_LAYERS 3
#define OUT_LEN 28
#define M_ROWS (BATCH * NN)   // 65536

typedef unsigned short u16;
typedef unsigned int   u32;
typedef __attribute__((ext_vector_type(8))) short short8;   // 8 f16 (4 VGPRs)
typedef __attribute__((ext_vector_type(4))) float f32x4;    // MFMA accumulator

// ---- fp16 split helpers (RNE casts) ----------------------------------------
__device__ __forceinline__ u16 f2h(float x) {
    union { _Float16 h; u16 u; } v; v.h = (_Float16)x; return v.u;
}
__device__ __forceinline__ float h2f(u16 u) {
    union { _Float16 h; u16 u; } v; v.u = u; return (float)v.h;
}

// async global -> LDS, 16 B per lane. LDS dest = wave-uniform base + lane*16.
__device__ __forceinline__ void gload_lds16(const void* g, void* l) {
    __builtin_amdgcn_global_load_lds(
        (const __attribute__((address_space(1))) void*)g,
        (__attribute__((address_space(3))) void*)l, 16, 0, 0);
}

// ---------------------------------------------------------------------------
// Split BOTH weight tensors into fp16 hi/lo (one launch).
// ---------------------------------------------------------------------------
__global__ __launch_bounds__(256)
void k_split2(const float* __restrict__ w1, const float* __restrict__ w2,
              u16* __restrict__ hi, u16* __restrict__ lo, int nW)
{
    int i = blockIdx.x * 256 + threadIdx.x;
    float v = (i < nW) ? w1[i] : w2[i - nW];
    u16 h = f2h(v);
    hi[i] = h;
    lo[i] = f2h(v - h2f(h));
}

// ---------------------------------------------------------------------------
// Kernel 1: ts = flat @ W_ts^T + b_ts ; h = concat([ts, node_emb]) -> split
// Vectorized: each thread owns a COLUMN PAIR and writes u32 (2 x fp16).
// ---------------------------------------------------------------------------
__global__ __launch_bounds__(256)
void k_ts(const float* __restrict__ x_node, const float* __restrict__ node_emb,
          const float* __restrict__ W_ts, const float* __restrict__ b_ts,
          u16* __restrict__ hhi, u16* __restrict__ hlo)
{
    __shared__ float xs[IN_LEN][64];
    const int tid = threadIdx.x;
    const int b   = blockIdx.y;
    const int n0  = blockIdx.x * 64;
    const int c   = tid & 127;        // col pair index
    const int sec = tid >> 7;         // 0: ts, 1: emb (wave-uniform)

    for (int idx = tid; idx < IN_LEN * 64; idx += 256) {
        int l = idx >> 6, i = idx & 63;
        xs[l][i] = x_node[((size_t)b * IN_LEN + l) * NN + n0 + i];
    }

    float w0[IN_LEN], w1[IN_LEN];
    float bias0 = 0.f, bias1 = 0.f;
    if (sec == 0) {
        #pragma unroll
        for (int j = 0; j < IN_LEN; j++) {
            w0[j] = W_ts[(2 * c) * IN_LEN + j];
            w1[j] = W_ts[(2 * c + 1) * IN_LEN + j];
        }
        bias0 = b_ts[2 * c];
        bias1 = b_ts[2 * c + 1];
    }
    __syncthreads();

    for (int i = 0; i < 64; i++) {
        size_t row = (size_t)b * NN + n0 + i;
        u32* oh = (u32*)(hhi + row * H);
        u32* ol = (u32*)(hlo + row * H);
        float v0, v1;
        int oc;
        if (sec == 0) {
            v0 = bias0; v1 = bias1;
            #pragma unroll
            for (int j = 0; j < IN_LEN; j++) {
                float x = xs[j][i];
                v0 += x * w0[j];
                v1 += x * w1[j];
            }
            oc = c;
        } else {
            const float2 ev = *(const float2*)&node_emb[(size_t)(n0 + i) * 256 + 2 * c];
            v0 = ev.x; v1 = ev.y;
            oc = 128 + c;
        }
        u16 h0 = f2h(v0), h1 = f2h(v1);
        oh[oc] = (u32)h0 | ((u32)h1 << 16);
        ol[oc] = (u32)f2h(v0 - h2f(h0)) | ((u32)f2h(v1 - h2f(h1)) << 16);
    }
}

// ---------------------------------------------------------------------------
// Kernel 2a: GEMM1  z = relu(h @ W1^T + b1), h split (3-term), z fp16 SINGLE.
// Tile 128x128, 4 waves, BK=32, all 4 tiles double-buffered (64 KB LDS),
// one barrier per K-step, XOR source swizzle, XCD-aware block decode.
// Epilogue: LDS-bounce then coalesced dwordx4 stores.
// ---------------------------------------------------------------------------
__global__ __launch_bounds__(256)
void k_gemm1(const u16* __restrict__ Ahi, const u16* __restrict__ Alo,
             const u16* __restrict__ Whi, const u16* __restrict__ Wlo,
             const float* __restrict__ bias, u16* __restrict__ Z)
{
    __shared__ __align__(16) u16 smem[32768];   // 64 KB

    const int tid = threadIdx.x;
    const int ln  = tid & 63;
    const int wv  = tid >> 6;

    const int id   = blockIdx.x;
    const int c    = (id >> 3) & 3;
    const int r    = (id & 7) | ((id >> 5) << 3);
    const int row0 = r * 128;
    const int col0 = c * 128;

    const int rbase = (wv & 1) * 64;
    const int cbase = (wv >> 1) * 64;

    const int lr = ln >> 2;
    const int lc = ln & 3;

    const u16* sgsrc; int sofs; int tb;
    if      (wv == 0) { sgsrc = Ahi; sofs = 0;     tb = row0; }
    else if (wv == 1) { sgsrc = Alo; sofs = 8192;  tb = row0; }
    else if (wv == 2) { sgsrc = Whi; sofs = 16384; tb = col0; }
    else              { sgsrc = Wlo; sofs = 24576; tb = col0; }

    auto stage = [&](int p, int kt) {
        u16* dstbuf = smem + sofs + p * 4096;
        #pragma unroll
        for (int i = 0; i < 8; i++) {
            int row = i * 16 + lr;
            int sc  = lc ^ ((row >> 1) & 3);
            gload_lds16(sgsrc + (size_t)(tb + row) * H + kt + sc * 8,
                        dstbuf + i * 512);
        }
    };

    f32x4 acc[4][4];
    #pragma unroll
    for (int m = 0; m < 4; m++)
        #pragma unroll
        for (int n = 0; n < 4; n++) acc[m][n] = (f32x4)(0.f);

    stage(0, 0);

    const int wl = ln & 15;

    for (int t = 0; t < 16; t++) {
        const int p = t & 1;
        __syncthreads();
        if (t + 1 < 16) stage(1 - p, (t + 1) * 32);

        const u16* bAh = smem + 0     + p * 4096;
        const u16* bAl = smem + 8192  + p * 4096;
        const u16* bWh = smem + 16384 + p * 4096;
        const u16* bWl = smem + 24576 + p * 4096;

        short8 ahi[4], alo[4], whi[4], wlo[4];
        #pragma unroll
        for (int m = 0; m < 4; m++) {
            int rr = rbase + m * 16 + wl;
            int cc = ((ln >> 4) ^ ((rr >> 1) & 3)) * 8;
            ahi[m] = *(const short8*)&bAh[rr * 32 + cc];
            alo[m] = *(const short8*)&bAl[rr * 32 + cc];
        }
        #pragma unroll
        for (int n = 0; n < 4; n++) {
            int wr = cbase + n * 16 + wl;
            int cc = ((ln >> 4) ^ ((wr >> 1) & 3)) * 8;
            whi[n] = *(const short8*)&bWh[wr * 32 + cc];
            wlo[n] = *(const short8*)&bWl[wr * 32 + cc];
        }
        #pragma unroll
        for (int m = 0; m < 4; m++)
            #pragma unroll
            for (int n = 0; n < 4; n++) {
                acc[m][n] = __builtin_amdgcn_mfma_f32_16x16x32_f16(ahi[m], whi[n], acc[m][n], 0, 0, 0);
                acc[m][n] = __builtin_amdgcn_mfma_f32_16x16x32_f16(ahi[m], wlo[n], acc[m][n], 0, 0, 0);
                acc[m][n] = __builtin_amdgcn_mfma_f32_16x16x32_f16(alo[m], whi[n], acc[m][n], 0, 0, 0);
            }
    }

    // ---- LDS-bounce epilogue ----
    __syncthreads();                         // staging LDS dead; reuse
    u16* zb = smem + wv * 4096;              // per-wave 64x64 u16 (8 KB)
    float bv[4];
    #pragma unroll
    for (int n = 0; n < 4; n++) bv[n] = bias[col0 + cbase + n * 16 + wl];
    #pragma unroll
    for (int m = 0; m < 4; m++)
        #pragma unroll
        for (int n = 0; n < 4; n++)
            #pragma unroll
            for (int rg = 0; rg < 4; rg++) {
                int row_l = m * 16 + (ln >> 4) * 4 + rg;
                zb[row_l * 64 + n * 16 + wl] =
                    f2h(fmaxf(acc[m][n][rg] + bv[n], 0.f));
            }
    const int cr = ln >> 3;          // 0..7
    const int cc = (ln & 7) * 8;     // u16 col
    #pragma unroll
    for (int p2 = 0; p2 < 8; p2++) {
        int row_l = cr + p2 * 8;
        uint4 v = *(const uint4*)&zb[row_l * 64 + cc];
        *(uint4*)&Z[(size_t)(row0 + rbase + row_l) * H + col0 + cbase + cc] = v;
    }
}

// ---------------------------------------------------------------------------
// Kernel 2b: GEMM2  h += z @ W2^T + b2, z fp16 single (2-term), out split.
// LDS K-loop = 48 KB. R8-style epilogue. HEAD=1 (last layer): fused b/g head
// GEMV; h_new is DEAD after the head (k_sir only needs bSum/gSum), so HEAD=1
// SKIPS the HHi/HLo stores entirely (~135 MB of write traffic deleted).
// ---------------------------------------------------------------------------
template <int HEAD>
__global__ __launch_bounds__(256)
void k_gemm2(const u16* __restrict__ Z,
             const u16* __restrict__ Whi, const u16* __restrict__ Wlo,
             const float* __restrict__ bias,
             u16* HHi, u16* HLo,
             const float* __restrict__ Wb, const float* __restrict__ Wg,
             float* __restrict__ bSum, float* __restrict__ gSum)
{
    __shared__ __align__(16) u16 smem[24576];   // 48 KB

    const int tid = threadIdx.x;
    const int ln  = tid & 63;
    const int wv  = tid >> 6;

    const int id   = blockIdx.x;
    const int c    = (id >> 3) & 3;
    const int r    = (id & 7) | ((id >> 5) << 3);
    const int row0 = r * 128;
    const int col0 = c * 128;

    const int rbase = (wv & 1) * 64;
    const int cbase = (wv >> 1) * 64;

    const int lr = ln >> 2;
    const int lc = ln & 3;

    const u16* sgsrc; int sofs; int tb; int iofs; int niss;
    if      (wv == 0) { sgsrc = Z;   sofs = 0;     tb = row0;      iofs = 0;    niss = 4; }
    else if (wv == 3) { sgsrc = Z;   sofs = 0;     tb = row0 + 64; iofs = 2048; niss = 4; }
    else if (wv == 1) { sgsrc = Whi; sofs = 8192;  tb = col0;      iofs = 0;    niss = 8; }
    else              { sgsrc = Wlo; sofs = 16384; tb = col0;      iofs = 0;    niss = 8; }

    auto stage = [&](int p, int kt) {
        u16* dstbuf = smem + sofs + p * 4096 + iofs;
        #pragma unroll
        for (int i = 0; i < 8; i++) {
            if (i >= niss) break;
            int row = i * 16 + lr;
            int sc  = lc ^ ((row >> 1) & 3);
            gload_lds16(sgsrc + (size_t)(tb + row) * H + kt + sc * 8,
                        dstbuf + i * 512);
        }
    };

    f32x4 acc[4][4];
    #pragma unroll
    for (int m = 0; m < 4; m++)
        #pragma unroll
        for (int n = 0; n < 4; n++) acc[m][n] = (f32x4)(0.f);

    stage(0, 0);

    const int wl = ln & 15;

    for (int t = 0; t < 16; t++) {
        const int p = t & 1;
        __syncthreads();
        if (t + 1 < 16) stage(1 - p, (t + 1) * 32);

        const u16* bZ  = smem + 0     + p * 4096;
        const u16* bWh = smem + 8192  + p * 4096;
        const u16* bWl = smem + 16384 + p * 4096;

        short8 az[4], whi[4], wlo[4];
        #pragma unroll
        for (int m = 0; m < 4; m++) {
            int rr = rbase + m * 16 + wl;
            int cc = ((ln >> 4) ^ ((rr >> 1) & 3)) * 8;
            az[m] = *(const short8*)&bZ[rr * 32 + cc];
        }
        #pragma unroll
        for (int n = 0; n < 4; n++) {
            int wr = cbase + n * 16 + wl;
            int cc = ((ln >> 4) ^ ((wr >> 1) & 3)) * 8;
            whi[n] = *(const short8*)&bWh[wr * 32 + cc];
            wlo[n] = *(const short8*)&bWl[wr * 32 + cc];
        }
        #pragma unroll
        for (int m = 0; m < 4; m++)
            #pragma unroll
            for (int n = 0; n < 4; n++) {
                acc[m][n] = __builtin_amdgcn_mfma_f32_16x16x32_f16(az[m], whi[n], acc[m][n], 0, 0, 0);
                acc[m][n] = __builtin_amdgcn_mfma_f32_16x16x32_f16(az[m], wlo[n], acc[m][n], 0, 0, 0);
            }
    }

    // ---- LDS-bounce RMW epilogue ----
    __syncthreads();                              // staging LDS dead; reuse
    float* fb = (float*)smem + wv * 2048;         // per-wave 64x32 f32 (8 KB)

    const int cr  = ln >> 3;           // 0..7
    const int ccl = (ln & 7) * 4;      // u16 col within 32
    float pb[8], pg[8];
    if (HEAD) {
        #pragma unroll
        for (int p2 = 0; p2 < 8; p2++) { pb[p2] = 0.f; pg[p2] = 0.f; }
    }

    #pragma unroll
    for (int nh = 0; nh < 2; nh++) {
        #pragma unroll
        for (int m = 0; m < 4; m++)
            #pragma unroll
            for (int j = 0; j < 2; j++)
                #pragma unroll
                for (int rg = 0; rg < 4; rg++) {
                    int row_l = m * 16 + (ln >> 4) * 4 + rg;
                    fb[row_l * 32 + j * 16 + wl] = acc[m][nh * 2 + j][rg];
                }
        const int gc0 = col0 + cbase + nh * 32 + ccl;
        float4 bv = *(const float4*)&bias[gc0];
        float4 hb, hg;
        if (HEAD) {
            hb = *(const float4*)&Wb[gc0];
            hg = *(const float4*)&Wg[gc0];
        }
        #pragma unroll
        for (int p2 = 0; p2 < 8; p2++) {
            int row_l = cr + p2 * 8;
            size_t gidx = (size_t)(row0 + rbase + row_l) * H + gc0;
            uint2 uh = *(const uint2*)(HHi + gidx);
            uint2 ul = *(const uint2*)(HLo + gidx);
            float4 a = *(const float4*)&fb[row_l * 32 + ccl];
            float v0 = a.x + bv.x + h2f((u16)(uh.x & 0xFFFF)) + h2f((u16)(ul.x & 0xFFFF));
            float v1 = a.y + bv.y + h2f((u16)(uh.x >> 16))    + h2f((u16)(ul.x >> 16));
            float v2 = a.z + bv.z + h2f((u16)(uh.y & 0xFFFF)) + h2f((u16)(ul.y & 0xFFFF));
            float v3 = a.w + bv.w + h2f((u16)(uh.y >> 16))    + h2f((u16)(ul.y >> 16));
            if (HEAD) {
                pb[p2] += v0 * hb.x + v1 * hb.y + v2 * hb.z + v3 * hb.w;
                pg[p2] += v0 * hg.x + v1 * hg.y + v2 * hg.z + v3 * hg.w;
            } else {
                u16 h0 = f2h(v0), h1 = f2h(v1), h2 = f2h(v2), h3 = f2h(v3);
                uint2 oh, ol;
                oh.x = (u32)h0 | ((u32)h1 << 16);
                oh.y = (u32)h2 | ((u32)h3 << 16);
                ol.x = (u32)f2h(v0 - h2f(h0)) | ((u32)f2h(v1 - h2f(h1)) << 16);
                ol.y = (u32)f2h(v2 - h2f(h2)) | ((u32)f2h(v3 - h2f(h3)) << 16);
                *(uint2*)(HHi + gidx) = oh;
                *(uint2*)(HLo + gidx) = ol;
            }
        }
    }

    if (HEAD) {
        #pragma unroll
        for (int p2 = 0; p2 < 8; p2++) {
            float sb = pb[p2], sg = pg[p2];
            #pragma unroll
            for (int off = 1; off < 8; off <<= 1) {
                sb += __shfl_xor(sb, off);
                sg += __shfl_xor(sg, off);
            }
            if ((ln & 7) == 0) {
                int grow = row0 + rbase + cr + p2 * 8;
                atomicAdd(&bSum[grow], sb);
                atomicAdd(&gSum[grow], sg);
            }
        }
    }
}

// ---------------------------------------------------------------------------
// Kernel 4: per-(b,n) SIR recurrence (applies head sigmoids itself).
// ---------------------------------------------------------------------------
__global__ __launch_bounds__(256)
void k_sir(const float* __restrict__ x_state,
           const float* __restrict__ bSum, const float* __restrict__ gSum,
           const float* __restrict__ bb, const float* __restrict__ bg,
           float* __restrict__ out)
{
    const int row = blockIdx.x * 256 + threadIdx.x;   // b*NN + n
    const int bb_ = row / NN;
    const int n   = row % NN;

    const float g = 1.f / (1.f + expf(-(gSum[row] + bg[0])));
    const float b = 1.f / (1.f + expf(-(bSum[row] + bb[0])));
    const float d = expf(-g);

    const float* xs = x_state + ((size_t)bb_ * IN_LEN) * (NN * 3) + (size_t)n * 3;

    float x1_prev = xs[1];
    float Ih_prev = x1_prev / g;
    float acc = 0.f;
    #pragma unroll 4
    for (int t = 1; t <= IN_LEN - 1; ++t) {
        float x1 = xs[(size_t)t * (NN * 3) + 1];
        float Ih = x1 / g;
        float Iin = fmaxf(Ih - Ih_prev + x1_prev, 0.f);
        acc = acc * d + Iin;
        Ih_prev = Ih;
        x1_prev = x1;
    }
    float ITm1 = acc * d;
    float Npop = xs[(size_t)(IN_LEN - 1) * (NN * 3) + 2];
    float RTm1 = Npop - xs[(size_t)(IN_LEN - 2) * (NN * 3) + 0];
    float STm1 = Npop - ITm1 - RTm1;
    float Iin0 = b * STm1 * ITm1 / Npop;
    float S = STm1 - Iin0;
    float I = d * (ITm1 + Iin0);

    float* op = out + ((size_t)bb_ * OUT_LEN) * NN + n;
    #pragma unroll 4
    for (int k = 0; k < OUT_LEN; k++) {
        float Iin = b * S * I / Npop;
        S = S - Iin;
        float Rin = g * I;
        I = d * (I + Iin);
        op[(size_t)k * NN] = Rin;
    }
}

// ---------------------------------------------------------------------------
extern "C" void kernel_launch(void* const* d_in, const int* in_sizes, int n_in,
                              void* d_out, int out_size, void* d_ws, size_t ws_size,
                              hipStream_t stream)
{
    const float* x_node   = (const float*)d_in[0];
    const float* x_state  = (const float*)d_in[1];
    const float* node_emb = (const float*)d_in[2];
    const float* W_ts     = (const float*)d_in[3];
    const float* b_ts     = (const float*)d_in[4];
    const float* enc_W1   = (const float*)d_in[5];
    const float* enc_b1   = (const float*)d_in[6];
    const float* enc_W2   = (const float*)d_in[7];
    const float* enc_b2   = (const float*)d_in[8];
    const float* Wb       = (const float*)d_in[9];
    const float* bb       = (const float*)d_in[10];
    const float* Wg       = (const float*)d_in[11];
    const float* bg       = (const float*)d_in[12];
    float* out = (float*)d_out;

    // Workspace: hhi 64M | hlo 64M | wHi 3M | wLo 3M | bSum | gSum | z (chunked)
    u16* hhi   = (u16*)d_ws;
    u16* hlo   = hhi + (size_t)M_ROWS * H;
    u16* wHi   = hlo + (size_t)M_ROWS * H;          // [6][512][512]
    u16* wLo   = wHi + (size_t)6 * H * H;
    float* bSum = (float*)(wLo + (size_t)6 * H * H);
    float* gSum = bSum + M_ROWS;
    u16* z     = (u16*)(gSum + M_ROWS);

    size_t used  = (size_t)((char*)z - (char*)d_ws);
    size_t avail = (ws_size > used) ? ws_size - used : 0;
    long long chunkLL = (long long)(avail / (H * sizeof(u16))) & ~1023LL;
    int chunk = (chunkLL > M_ROWS) ? M_ROWS : (int)chunkLL;
    if (chunk < 1024) chunk = 1024;
    // (R11 measured: L3 already absorbs the h/z re-reads; row-chunking through
    // layers added dispatch overhead with no fetch reduction. Full-M it is.)

    // zero the head accumulators (d_ws is re-poisoned before every call)
    hipMemsetAsync(bSum, 0, 2 * (size_t)M_ROWS * sizeof(float), stream);

    // weight conversion (redone every call)
    const int nW = N_LAYERS * H * H;   // 786432
    k_split2<<<2 * nW / 256, 256, 0, stream>>>(enc_W1, enc_W2, wHi, wLo, nW);

    // 1. build h (split)
    k_ts<<<dim3(NN / 64, BATCH), 256, 0, stream>>>(x_node, node_emb, W_ts, b_ts, hhi, hlo);

    // 2. encoder layers
    for (int l = 0; l < N_LAYERS; l++) {
        const u16* W1hi = wHi + (size_t)l * H * H;
        const u16* W1lo = wLo + (size_t)l * H * H;
        const u16* W2hi = wHi + (size_t)nW + (size_t)l * H * H;
        const u16* W2lo = wLo + (size_t)nW + (size_t)l * H * H;
        const float* b1 = enc_b1 + (size_t)l * H;
        const float* b2 = enc_b2 + (size_t)l * H;
        for (int r = 0; r < M_ROWS; r += chunk) {
            int rows = (M_ROWS - r < chunk) ? (M_ROWS - r) : chunk;
            u16* hrhi = hhi + (size_t)r * H;
            u16* hrlo = hlo + (size_t)r * H;
            int nblk = (rows / 128) * 4;
            k_gemm1<<<nblk, 256, 0, stream>>>(hrhi, hrlo, W1hi, W1lo, b1, z);
            if (l < N_LAYERS - 1)
                k_gemm2<0><<<nblk, 256, 0, stream>>>(z, W2hi, W2lo, b2, hrhi, hrlo,
                                                     Wb, Wg, bSum + r, gSum + r);
            else
                k_gemm2<1><<<nblk, 256, 0, stream>>>(z, W2hi, W2lo, b2, hrhi, hrlo,
                                                     Wb, Wg, bSum + r, gSum + r);
        }
    }

    // 3. SIR recurrence + output (head sigmoid fused)
    k_sir<<<M_ROWS / 256, 256, 0, stream>>>(x_state, bSum, gSum, bb, bg, out);
}